// Round 1
// baseline (1745.512 us; speedup 1.0000x reference)
//
#include <hip/hip_runtime.h>
#include <stdint.h>

// LSTM: BATCH=64, SEQ=512, INPUT=512, UNITS=512, gates i,f,g,o.
// R4: critical chain = h-MFMA -> in-register gate fusion -> tagged publish -> spin.
// x@Wx is computed for t+1 AFTER publishing h(t) (hidden under the spin wait).
// R5: spin loop rewritten from 8x 8B atomic loads (64 uncoalesced line-transactions
// per wave-instr -> MALL request-rate congestion) to 4x wave-coalesced
// global_load_dwordx4 sc0 sc1 (same L1/L2-bypass semantics, same addresses,
// per-u64 tags still verified -> correctness preserved). ~8x fewer memory-side
// requests per poll round.

#define OFF_XBF   0ull                    // bf16 x [64][512][512]  (32 MB)
#define OFF_HU    33562624ull             // u64 H[2][64][256]: (tag<<32)|bf16pair

typedef short short8 __attribute__((ext_vector_type(8)));
typedef float f32x4 __attribute__((ext_vector_type(4)));
typedef unsigned u32x4 __attribute__((ext_vector_type(4)));

__device__ __forceinline__ unsigned f32_to_bf16(float f) {
    union { float f; unsigned u; } v; v.f = f;
    unsigned u = v.u;
    unsigned r = u + 0x7FFFu + ((u >> 16) & 1u);   // RNE
    return r >> 16;
}

__global__ void prep_kernel(const float* __restrict__ x,
                            const float* __restrict__ h0,
                            unsigned char* __restrict__ ws) {
    long long i = (long long)blockIdx.x * blockDim.x + threadIdx.x;
    if (i < 2097152) {   // x -> bf16, 8 elements/thread
        const float4* xs = (const float4*)x + i * 2;
        float4 a = xs[0], b = xs[1];
        unsigned w0 = f32_to_bf16(a.x) | (f32_to_bf16(a.y) << 16);
        unsigned w1 = f32_to_bf16(a.z) | (f32_to_bf16(a.w) << 16);
        unsigned w2 = f32_to_bf16(b.x) | (f32_to_bf16(b.y) << 16);
        unsigned w3 = f32_to_bf16(b.z) | (f32_to_bf16(b.w) << 16);
        uint4 o; o.x = w0; o.y = w1; o.z = w2; o.w = w3;
        ((uint4*)(ws + OFF_XBF))[i] = o;
        return;
    }
    i -= 2097152;
    if (i < 16384) {     // H[0] <- h0, tag=1
        int b = (int)(i >> 8), p = (int)(i & 255);
        unsigned lo = f32_to_bf16(h0[b * 512 + 2 * p]);
        unsigned hi = f32_to_bf16(h0[b * 512 + 2 * p + 1]);
        ((unsigned long long*)(ws + OFF_HU))[(long long)b * 256 + p] =
            (unsigned long long)(lo | (hi << 16)) | (1ull << 32);
    }
}

// Wide spin: 4x dwordx4 sc0/sc1 loads over this thread's contiguous 64B tag+data
// region; every u64 carries its own tag so a retry loop keeps full correctness.
#define SPIN_LOAD(BASEPTR, TAGV, H0V, H1V)                                     \
    {                                                                          \
        u32x4 p0, p1, p2, p3;                                                  \
        for (;;) {                                                             \
            asm volatile(                                                      \
                "global_load_dwordx4 %0, %4, off sc0 sc1\n\t"                  \
                "global_load_dwordx4 %1, %4, off offset:16 sc0 sc1\n\t"        \
                "global_load_dwordx4 %2, %4, off offset:32 sc0 sc1\n\t"        \
                "global_load_dwordx4 %3, %4, off offset:48 sc0 sc1\n\t"        \
                "s_waitcnt vmcnt(0)"                                           \
                : "=v"(p0), "=v"(p1), "=v"(p2), "=v"(p3)                       \
                : "v"(BASEPTR)                                                 \
                : "memory");                                                   \
            unsigned bad = (p0.y ^ (TAGV)) | (p0.w ^ (TAGV))                   \
                         | (p1.y ^ (TAGV)) | (p1.w ^ (TAGV))                   \
                         | (p2.y ^ (TAGV)) | (p2.w ^ (TAGV))                   \
                         | (p3.y ^ (TAGV)) | (p3.w ^ (TAGV));                  \
            if (!bad) {                                                        \
                H0V.x = p0.x; H0V.y = p0.z; H0V.z = p1.x; H0V.w = p1.z;        \
                H1V.x = p2.x; H1V.y = p2.z; H1V.z = p3.x; H1V.w = p3.z;        \
                break;                                                         \
            }                                                                  \
            __builtin_amdgcn_s_sleep(0);                                       \
        }                                                                      \
    }

// LDS: xbuf [8][1040B] @0, hbuf [8][1040B] @8320, out-ring [8][8][16]f32 @16640 (4KB)
__launch_bounds__(256, 1)
__global__ void lstm_kernel(const float* __restrict__ c0,
                            const float* __restrict__ bias,
                            const float* __restrict__ Wx,
                            const float* __restrict__ Wh,
                            float* __restrict__ out,
                            unsigned char* __restrict__ ws) {
    const int tid  = threadIdx.x;
    const int bid  = blockIdx.x;
    const int s    = bid & 7;      // sample group: batches 8s..8s+7
    const int jg   = bid >> 3;     // unit group: units 16jg..16jg+15
    const int lane = tid & 63;
    const int wave = tid >> 6;
    const int nl   = lane & 15;
    const int q    = lane >> 4;
    const int up   = nl & 3;       // unit-in-wave 0..3
    const int g    = nl >> 2;      // gate slot 0..3

    const unsigned short* xbf = (const unsigned short*)(ws + OFF_XBF);
    unsigned long long* Hu = (unsigned long long*)(ws + OFF_HU);

    __shared__ __align__(16) unsigned char lds[20736];
    float* lds_out = (float*)(lds + 16640);

    // persistent fragments: this wave covers cols {g*512 + jg*16 + wave*4 + up},
    // i.e. all 4 gates of 4 units, full K. B[n=lane&15][k=q*8+j] per k-tile.
    const int ncol = g * 512 + jg * 16 + wave * 4 + up;
    short8 fWh[16], fWx[16];
#pragma unroll
    for (int kt = 0; kt < 16; ++kt) {
        const int k0 = kt * 32 + q * 8;
        short8 vh, vx;
#pragma unroll
        for (int j = 0; j < 8; ++j) {
            vh[j] = (short)f32_to_bf16(Wh[(long long)(k0 + j) * 2048 + ncol]);
            vx[j] = (short)f32_to_bf16(Wx[(long long)(k0 + j) * 2048 + ncol]);
        }
        fWh[kt] = vh; fWx[kt] = vx;
    }

    const int ub = jg * 16 + wave * 4 + up;     // this lane's unit (global)
    const float bi  = bias[ub];
    const float bf_ = bias[512 + ub];
    const float bg  = bias[1024 + ub];
    const float bo  = bias[1536 + ub];

    float cr[4];
#pragma unroll
    for (int r = 0; r < 4; ++r) {
        const int m = q * 4 + r;
        cr[r] = (q < 2) ? c0[(8 * s + m) * 512 + ub] : 0.f;
    }

    // staging map: thread -> (row sm, 64B chunk sc) of the 8x512 slice
    const int sm = tid >> 5, sc = tid & 31;
    const int sb = 8 * s + sm;
    const unsigned* xsrc_base = (const unsigned*)xbf + (long long)sb * 131072 + sc * 8;
    unsigned long long* hsrc_base = Hu + sb * 256 + sc * 8;
    uint4* xdst = (uint4*)(lds + sm * 1040 + sc * 32);
    uint4* hdst = (uint4*)(lds + 8320 + sm * 1040 + sc * 32);

    // A-fragment read base (only lanes nl<8 read; others feed zero frags)
    const unsigned char* axp = lds + nl * 1040 + q * 16;
    const unsigned char* ahp = lds + 8320 + nl * 1040 + q * 16;
    const short8 zfrag = {0, 0, 0, 0, 0, 0, 0, 0};

    // shfl source lanes for gate gather (same q, same up, gate slot varies)
    const int gbase = (lane & 0x30) | (lane & 3);
    const int sl0 = gbase, sl1 = gbase | 4, sl2 = gbase | 8, sl3 = gbase | 12;

    // ---- prologue: stage x(0), accx = x(0)@Wx, stage h0 ----
    uint4 px0 = *(const uint4*)(xsrc_base);
    uint4 px1 = *(const uint4*)(xsrc_base + 4);
    xdst[0] = px0; xdst[1] = px1;
    px0 = *(const uint4*)(xsrc_base + 256);
    px1 = *(const uint4*)(xsrc_base + 256 + 4);
    __syncthreads();

    f32x4 accx;
    {
        f32x4 a0 = {0.f,0.f,0.f,0.f}, a1 = {0.f,0.f,0.f,0.f};
#pragma unroll
        for (int kt = 0; kt < 16; kt += 2) {
            short8 v0 = (nl < 8) ? *(const short8*)(axp + kt * 64) : zfrag;
            short8 v1 = (nl < 8) ? *(const short8*)(axp + kt * 64 + 64) : zfrag;
            a0 = __builtin_amdgcn_mfma_f32_16x16x32_bf16(v0, fWx[kt], a0, 0, 0, 0);
            a1 = __builtin_amdgcn_mfma_f32_16x16x32_bf16(v1, fWx[kt + 1], a1, 0, 0, 0);
        }
        accx = a0 + a1;
    }
    {   // spin h0 (tag 1, buffer 0) and stage — wide coalesced poll
        const unsigned char* hs0 = (const unsigned char*)hsrc_base;
        uint4 h0v, h1v;
        SPIN_LOAD(hs0, 1u, h0v, h1v);
        hdst[0] = h0v; hdst[1] = h1v;
    }
    __syncthreads();

    for (int t = 0; t < 512; ++t) {
        const int wb = (t + 1) & 1;

        // ---- 1: acch = h(t-1)@Wh  [critical chain] ----
        f32x4 acch;
        {
            f32x4 a0 = {0.f,0.f,0.f,0.f}, a1 = {0.f,0.f,0.f,0.f};
#pragma unroll
            for (int kt = 0; kt < 16; kt += 2) {
                short8 v0 = (nl < 8) ? *(const short8*)(ahp + kt * 64) : zfrag;
                short8 v1 = (nl < 8) ? *(const short8*)(ahp + kt * 64 + 64) : zfrag;
                a0 = __builtin_amdgcn_mfma_f32_16x16x32_bf16(v0, fWh[kt], a0, 0, 0, 0);
                a1 = __builtin_amdgcn_mfma_f32_16x16x32_bf16(v1, fWh[kt + 1], a1, 0, 0, 0);
            }
            acch = a0 + a1;
        }

        // ---- 2: gate fusion in registers (4 shfl gathers per row) ----
        float hn[4]; unsigned hb[4];
#pragma unroll
        for (int r = 0; r < 4; ++r) {
            float zs = accx[r] + acch[r];
            float z0 = __shfl(zs, sl0, 64) + bi;
            float z1 = __shfl(zs, sl1, 64) + bf_;
            float z2 = __shfl(zs, sl2, 64) + bg;
            float z3 = __shfl(zs, sl3, 64) + bo;
            float ig = __fdividef(1.f, 1.f + __expf(-z0));
            float fg = __fdividef(1.f, 1.f + __expf(-z1));
            float z2c = fminf(fmaxf(z2, -20.f), 20.f);
            float e2 = __expf(2.f * z2c);
            float gg = __fdividef(e2 - 1.f, e2 + 1.f);
            float og = __fdividef(1.f, 1.f + __expf(-z3));
            float cn = fg * cr[r] + ig * gg;
            cr[r] = cn;
            float cnc = fminf(fmaxf(cn, -20.f), 20.f);
            float ec = __expf(2.f * cnc);
            hn[r] = og * __fdividef(ec - 1.f, ec + 1.f);
            hb[r] = f32_to_bf16(hn[r]);
        }
        unsigned oth[4];
#pragma unroll
        for (int r = 0; r < 4; ++r)
            oth[r] = (unsigned)__shfl((int)hb[r], lane ^ 1, 64);

        // ---- 3: publish h(t) (end of chain head) + out-ring write ----
        if (q < 2 && g == 0) {
#pragma unroll
            for (int r = 0; r < 4; ++r)
                lds_out[(t & 7) * 128 + (q * 4 + r) * 16 + wave * 4 + up] = hn[r];
            if ((up & 1) == 0) {
#pragma unroll
                for (int r = 0; r < 4; ++r) {
                    unsigned long long v = (unsigned long long)(hb[r] | (oth[r] << 16))
                                         | ((unsigned long long)(unsigned)(t + 2) << 32);
                    __hip_atomic_store(Hu + (size_t)wb * 16384 + (8 * s + q * 4 + r) * 256
                                           + jg * 8 + wave * 2 + (up >> 1),
                                       v, __ATOMIC_RELAXED, __HIP_MEMORY_SCOPE_AGENT);
                }
            }
        }

        // ---- 4: stage x(t+1) from prefetch; issue prefetch t+2 [off-chain] ----
        xdst[0] = px0; xdst[1] = px1;
        {
            const int tp = (t + 2 < 512) ? (t + 2) : 511;
            px0 = *(const uint4*)(xsrc_base + tp * 256);
            px1 = *(const uint4*)(xsrc_base + tp * 256 + 4);
        }
        __syncthreads();   // S0

        // out burst every 8 steps (coalesced float4)
        if ((t & 7) == 7) {
            const int stp = tid >> 5, brow = (tid >> 2) & 7, qd = tid & 3;
            float4 v = *(const float4*)(lds_out + stp * 128 + brow * 16 + qd * 4);
            *(float4*)(out + (long long)(t - 7 + stp) * 32768
                           + (8 * s + brow) * 512 + jg * 16 + qd * 4) = v;
        }

        // ---- 5: accx = x(t+1)@Wx [hidden under spin] ----
        {
            f32x4 a0 = {0.f,0.f,0.f,0.f}, a1 = {0.f,0.f,0.f,0.f};
#pragma unroll
            for (int kt = 0; kt < 16; kt += 2) {
                short8 v0 = (nl < 8) ? *(const short8*)(axp + kt * 64) : zfrag;
                short8 v1 = (nl < 8) ? *(const short8*)(axp + kt * 64 + 64) : zfrag;
                a0 = __builtin_amdgcn_mfma_f32_16x16x32_bf16(v0, fWx[kt], a0, 0, 0, 0);
                a1 = __builtin_amdgcn_mfma_f32_16x16x32_bf16(v1, fWx[kt + 1], a1, 0, 0, 0);
            }
            accx = a0 + a1;
        }

        // ---- 6: spin on h(t) tags (wide coalesced poll); stage into hbuf ----
        {
            const unsigned char* hs = (const unsigned char*)hsrc_base
                                    + (size_t)wb * 131072;
            const unsigned tag = (unsigned)(t + 2);
            uint4 h0v, h1v;
            SPIN_LOAD(hs, tag, h0v, h1v);
            hdst[0] = h0v; hdst[1] = h1v;
        }
        __syncthreads();   // S1
    }
}

extern "C" void kernel_launch(void* const* d_in, const int* in_sizes, int n_in,
                              void* d_out, int out_size, void* d_ws, size_t ws_size,
                              hipStream_t stream) {
    const float* x  = (const float*)d_in[0];
    const float* h0 = (const float*)d_in[1];
    const float* c0 = (const float*)d_in[2];
    const float* Wx = (const float*)d_in[3];
    const float* Wh = (const float*)d_in[4];
    const float* b  = (const float*)d_in[5];
    unsigned char* ws = (unsigned char*)d_ws;
    float* out = (float*)d_out;

    const long long n0 = 2097152 + 16384;
    const int blocks0 = (int)((n0 + 255) / 256);
    hipLaunchKernelGGL(prep_kernel, dim3(blocks0), dim3(256), 0, stream, x, h0, ws);
    hipLaunchKernelGGL(lstm_kernel, dim3(256), dim3(256), 0, stream,
                       c0, b, Wx, Wh, out, ws);
}